// Round 8
// baseline (455.545 us; speedup 1.0000x reference)
//
#include <hip/hip_runtime.h>
#include <hip/hip_bf16.h>
#include <cmath>

typedef __bf16 bf16;
typedef __bf16 bf16x4 __attribute__((ext_vector_type(4)));
typedef __bf16 bf16x8 __attribute__((ext_vector_type(8)));
typedef float f32x4 __attribute__((ext_vector_type(4)));

#define BB 2
#define SS 2048
#define DD 1024
#define HH 16
#define WW 16
#define HDD 64
#define DFFD 4096
#define NTOK (BB*SS)

__device__ __forceinline__ float gelu_f(float x) {
    const float c = 0.7978845608028654f;  // sqrt(2/pi)
    float t = tanhf(c * (x + 0.044715f * x * x * x));
    return 0.5f * x * (1.0f + t);
}

// ---- async global->LDS 16B/lane. LDS dest = wave-uniform base + lane*16 (m104/m108). ----
__device__ __forceinline__ void glds16(const bf16* g, const bf16* l) {
    __builtin_amdgcn_global_load_lds(
        (const __attribute__((address_space(1))) void*)(uintptr_t)(const void*)g,
        (__attribute__((address_space(3))) void*)(unsigned)(uintptr_t)(const void*)l,
        16, 0, 0);
}

// ---------------- fp32 -> bf16 convert, 8 elems/thread ----------------
__global__ __launch_bounds__(256) void conv_kernel(
    const float* __restrict__ src, bf16* __restrict__ dst, int n8)
{
    int i = blockIdx.x * 256 + threadIdx.x;
    if (i >= n8) return;
    f32x4 a = *(const f32x4*)(src + (size_t)i * 8);
    f32x4 b = *(const f32x4*)(src + (size_t)i * 8 + 4);
    bf16x8 v;
#pragma unroll
    for (int j = 0; j < 4; j++) { v[j] = (bf16)a[j]; v[4 + j] = (bf16)b[j]; }
    *(bf16x8*)(dst + (size_t)i * 8) = v;
}

// ---------------- d_out init: out[row,col] = x[row,col] + bias[col] ----------------
__global__ __launch_bounds__(256) void init_resid_kernel(
    const float* __restrict__ x, const float* __restrict__ bias, float* __restrict__ out)
{
    const int row = blockIdx.x, t = threadIdx.x;
    const size_t idx = (size_t)row * DD + t * 4;
    f32x4 v = *(const f32x4*)(x + idx);
    f32x4 bv = *(const f32x4*)(bias + t * 4);
#pragma unroll
    for (int i = 0; i < 4; i++) v[i] += bv[i];
    *(f32x4*)(out + idx) = v;
}

// ---------------- fused LayerNorm: fp32 row -> bf16 row, one block/row ----------------
__global__ __launch_bounds__(256) void ln_kernel(
    const float* __restrict__ x, const float* __restrict__ g, const float* __restrict__ b,
    bf16* __restrict__ out)
{
    const int row = blockIdx.x, t = threadIdx.x;
    f32x4 v = *(const f32x4*)(x + (size_t)row * DD + t * 4);
    float s  = v[0] + v[1] + v[2] + v[3];
    float s2 = v[0]*v[0] + v[1]*v[1] + v[2]*v[2] + v[3]*v[3];
#pragma unroll
    for (int off = 32; off >= 1; off >>= 1) {
        s  += __shfl_xor(s,  off, 64);
        s2 += __shfl_xor(s2, off, 64);
    }
    __shared__ float red[8];
    const int wave = t >> 6;
    if ((t & 63) == 0) { red[wave] = s; red[4 + wave] = s2; }
    __syncthreads();
    float ts  = red[0] + red[1] + red[2] + red[3];
    float ts2 = red[4] + red[5] + red[6] + red[7];
    float mean = ts * (1.0f / DD);
    float var  = ts2 * (1.0f / DD) - mean * mean;
    float rstd = rsqrtf(var + 1e-5f);
    f32x4 gv = *(const f32x4*)(g + t * 4);
    f32x4 bv = *(const f32x4*)(b + t * 4);
    bf16x4 o;
#pragma unroll
    for (int i = 0; i < 4; i++) o[i] = (bf16)((v[i] - mean) * rstd * gv[i] + bv[i]);
    *(bf16x4*)(out + (size_t)row * DD + t * 4) = o;
}

// ---------------- bf16 MFMA GEMM w/ global_load_lds: C[M,N] = A[M,K] @ W[N,K]^T + bias ----
// TM: 128 (waves 2x2, 4x4 frags) or 64 (waves 1x4, 4x2 frags). BN=128, BK=32, 256 thr.
// ACT: 1=gelu. OUTF32: 1=fp32 out. SPLIT: K-split count; >1 => fp32 atomic-accumulate
// into Cout (pre-initialized with residual), bias added by kz==0 only, BIAS flag.
template<int TM, int ACT, int OUTF32, int SPLIT, int BIAS>
__global__ __launch_bounds__(256) void gemm_glds(
    const bf16* __restrict__ A, const bf16* __restrict__ Bw,
    const float* __restrict__ bias,
    void* __restrict__ Cout, int N, int K)
{
    constexpr int MI = 4;
    constexpr int NJ = (TM == 128) ? 4 : 2;
    __shared__ __align__(16) bf16 As[TM * 32];
    __shared__ __align__(16) bf16 Bs[128 * 32];
    const int t = threadIdx.x;
    const int m0 = blockIdx.y * TM, n0 = blockIdx.x * 128;
    const int kz = (SPLIT > 1) ? blockIdx.z : 0;
    const int Ksl = K / SPLIT;
    const int kbeg = kz * Ksl;
    const int lane = t & 63, w = t >> 6;
    const int wm = (TM == 128) ? (w & 1) * 64 : 0;
    const int wn = (TM == 128) ? (w >> 1) * 64 : w * 32;
    const int quad = lane >> 4, l16 = lane & 15;
    const int srow = t >> 2, scol = (t & 3) * 8;   // 4 lanes/row, 8 bf16 (16 B) each

    const bf16* Ag = A  + (size_t)(m0 + srow) * K + scol + kbeg;
    const bf16* Bg = Bw + (size_t)(n0 + srow) * K + scol + kbeg;
    const bf16* AsW = As + w * 512;   // wave-uniform LDS base
    const bf16* BsW = Bs + w * 512;

    const f32x4 zero = {0.f, 0.f, 0.f, 0.f};
    f32x4 acc[MI][NJ];
#pragma unroll
    for (int i = 0; i < MI; i++)
#pragma unroll
        for (int j = 0; j < NJ; j++) acc[i][j] = zero;

    for (int k0 = 0; k0 < Ksl; k0 += 32) {
        __syncthreads();                       // all waves done reading previous tile
        glds16(Ag + k0, AsW);
        if (TM == 128) glds16(Ag + (size_t)64 * K + k0, AsW + 2048);
        glds16(Bg + k0, BsW);
        glds16(Bg + (size_t)64 * K + k0, BsW + 2048);
        __syncthreads();                       // drains vmcnt -> LDS tiles visible
        bf16x8 af[MI], bfr[NJ];
#pragma unroll
        for (int i = 0; i < MI; i++)
            af[i] = *(const bf16x8*)(As + (wm + i * 16 + l16) * 32 + quad * 8);
#pragma unroll
        for (int j = 0; j < NJ; j++)
            bfr[j] = *(const bf16x8*)(Bs + (wn + j * 16 + l16) * 32 + quad * 8);
#pragma unroll
        for (int i = 0; i < MI; i++)
#pragma unroll
            for (int j = 0; j < NJ; j++)
                acc[i][j] = __builtin_amdgcn_mfma_f32_16x16x32_bf16(af[i], bfr[j], acc[i][j], 0, 0, 0);
    }

#pragma unroll
    for (int i = 0; i < MI; i++) {
#pragma unroll
        for (int j = 0; j < NJ; j++) {
            int col = n0 + wn + j * 16 + l16;
            float bv = (BIAS && (SPLIT == 1 || kz == 0)) ? bias[col] : 0.f;
#pragma unroll
            for (int r = 0; r < 4; r++) {
                int row = m0 + wm + i * 16 + quad * 4 + r;
                float val = acc[i][j][r] + bv;
                if (ACT == 1) val = gelu_f(val);
                size_t idx = (size_t)row * N + col;
                if (SPLIT > 1) {
                    unsafeAtomicAdd((float*)Cout + idx, val);  // native global_atomic_add_f32
                } else if (OUTF32) {
                    ((float*)Cout)[idx] = val;
                } else {
                    ((bf16*)Cout)[idx] = (bf16)val;
                }
            }
        }
    }
}

// ---------------- Sliding-window causal attention: one wave per (b,h,q) ----------------
__global__ __launch_bounds__(256) void attn_kernel(
    const bf16* __restrict__ qkv, bf16* __restrict__ o)
{
    const int gw = blockIdx.x * 4 + (threadIdx.x >> 6);
    const int lane = threadIdx.x & 63;
    const int q = gw & (SS - 1);
    const int h = (gw >> 11) & (HH - 1);
    const int b = gw >> 15;
    const size_t rowstride = 3 * DD;
    const bf16* base = qkv + (size_t)b * SS * rowstride + h * HDD + lane;
    float qd = (float)base[(size_t)q * rowstride] * 0.125f;  // 1/sqrt(64)
    float kv[WW], vv[WW];
#pragma unroll
    for (int j = 0; j < WW; j++) {
        int key = q - (WW - 1) + j;
        int kc = key < 0 ? 0 : key;
        const bf16* kp = base + (size_t)kc * rowstride + DD;
        kv[j] = (float)kp[0];
        vv[j] = (float)kp[DD];
    }
    float sc[WW];
#pragma unroll
    for (int j = 0; j < WW; j++) {
        float p = qd * kv[j];
        p += __shfl_xor(p, 32, 64);
        p += __shfl_xor(p, 16, 64);
        p += __shfl_xor(p,  8, 64);
        p += __shfl_xor(p,  4, 64);
        p += __shfl_xor(p,  2, 64);
        p += __shfl_xor(p,  1, 64);
        sc[j] = (q - (WW - 1) + j >= 0) ? p : -1e30f;
    }
    float m = sc[0];
#pragma unroll
    for (int j = 1; j < WW; j++) m = fmaxf(m, sc[j]);
    float l = 0.f, od = 0.f;
#pragma unroll
    for (int j = 0; j < WW; j++) {
        float e = __expf(sc[j] - m);
        l += e;
        od += e * vv[j];
    }
    o[(size_t)(b * SS + q) * DD + h * HDD + lane] = (bf16)(od / l);
}

// ---------------- launch ----------------
extern "C" void kernel_launch(void* const* d_in, const int* in_sizes, int n_in,
                              void* d_out, int out_size, void* d_ws, size_t ws_size,
                              hipStream_t stream)
{
    (void)in_sizes; (void)n_in; (void)out_size; (void)ws_size;
    const float* x    = (const float*)d_in[0];
    const float* ln1g = (const float*)d_in[1];
    const float* ln1b = (const float*)d_in[2];
    const float* Wqkv = (const float*)d_in[3];
    const float* bqkv = (const float*)d_in[4];
    const float* Wout = (const float*)d_in[5];
    const float* bout = (const float*)d_in[6];
    const float* ln2g = (const float*)d_in[7];
    const float* ln2b = (const float*)d_in[8];
    const float* W1   = (const float*)d_in[9];
    const float* b1   = (const float*)d_in[10];
    const float* W2   = (const float*)d_in[11];
    const float* b2   = (const float*)d_in[12];

    // Workspace (56 MiB peak; proven safe in R2):
    //   [0,16M)  W region. Phase A: Wqkv_bf @0..6M, Wout_bf @6..8M.
    //            Phase B: W1_bf @0..8M, W2_bf @8..16M.
    //   [16,48M) P region. Phase A: qkv bf16 24 MiB. Phase B: h1 bf16 32 MiB.
    //   [48,56M) H region: h (LN1 out) -> o (attn out) -> xn (LN2 out), serially.
    //   x1 fp32 lives in d_out (pre-init x+bout, atomically accumulated by out-proj;
    //   MLP2 atomically accumulates onto it in place).
    const size_t MB = (size_t)1 << 20;
    char* ws = (char*)d_ws;
    bf16* wqkv_bf = (bf16*)(ws);
    bf16* wout_bf = (bf16*)(ws + 6 * MB);
    bf16* w1_bf   = (bf16*)(ws);
    bf16* w2_bf   = (bf16*)(ws + 8 * MB);
    bf16* qkv     = (bf16*)(ws + 16 * MB);
    bf16* h1      = (bf16*)(ws + 16 * MB);
    bf16* hbuf    = (bf16*)(ws + 48 * MB);   // h, then o, then xn
    float* x1     = (float*)d_out;

    const dim3 blk(256);

    // Phase A: weights for QKV + out-proj
    conv_kernel<<<(3 * DD * DD / 8) / 256, blk, 0, stream>>>(Wqkv, wqkv_bf, 3 * DD * DD / 8);
    conv_kernel<<<(DD * DD / 8) / 256, blk, 0, stream>>>(Wout, wout_bf, DD * DD / 8);
    // h = LN1(x)
    ln_kernel<<<NTOK, blk, 0, stream>>>(x, ln1g, ln1b, hbuf);
    // qkv = h @ Wqkv^T + bqkv           (M=4096, N=3072, K=1024)
    gemm_glds<128, 0, 0, 1, 1><<<dim3(24, 32), blk, 0, stream>>>(
        hbuf, wqkv_bf, bqkv, qkv, 3 * DD, DD);
    // o = attention(qkv)  (o overwrites h — h dead)
    attn_kernel<<<BB * HH * SS / 4, blk, 0, stream>>>(qkv, hbuf);
    // x1 = x + bout (init), then += o @ Wout^T  (split-K=2 atomic; M=4096, N=1024, K=1024)
    init_resid_kernel<<<NTOK, blk, 0, stream>>>(x, bout, x1);
    gemm_glds<64, 0, 1, 2, 0><<<dim3(8, 64, 2), blk, 0, stream>>>(
        hbuf, wout_bf, nullptr, x1, DD, DD);

    // Phase B: weights for MLP
    conv_kernel<<<(DFFD * DD / 8) / 256, blk, 0, stream>>>(W1, w1_bf, DFFD * DD / 8);
    conv_kernel<<<(DFFD * DD / 8) / 256, blk, 0, stream>>>(W2, w2_bf, DFFD * DD / 8);
    // xn = LN2(x1)   (xn overwrites o — o dead)
    ln_kernel<<<NTOK, blk, 0, stream>>>(x1, ln2g, ln2b, hbuf);
    // h1 = gelu(xn @ W1^T + b1)         (M=4096, N=4096, K=1024; h1 overwrites qkv)
    gemm_glds<128, 1, 0, 1, 1><<<dim3(32, 32), blk, 0, stream>>>(
        hbuf, w1_bf, b1, h1, DFFD, DD);
    // out = x1 + h1 @ W2^T + b2         (split-K=4 atomic in-place; M=4096, N=1024, K=4096)
    gemm_glds<64, 0, 1, 4, 1><<<dim3(8, 64, 4), blk, 0, stream>>>(
        h1, w2_bf, b2, x1, DD, DFFD);
}

// Round 10
// 428.123 us; speedup vs baseline: 1.0641x; 1.0641x over previous
//
#include <hip/hip_runtime.h>
#include <hip/hip_bf16.h>
#include <cmath>

typedef __bf16 bf16;
typedef __bf16 bf16x4 __attribute__((ext_vector_type(4)));
typedef __bf16 bf16x8 __attribute__((ext_vector_type(8)));
typedef float f32x4 __attribute__((ext_vector_type(4)));

#define BB 2
#define SS 2048
#define DD 1024
#define HH 16
#define WW 16
#define HDD 64
#define DFFD 4096
#define NTOK (BB*SS)

__device__ __forceinline__ float gelu_f(float x) {
    const float c = 0.7978845608028654f;  // sqrt(2/pi)
    float t = tanhf(c * (x + 0.044715f * x * x * x));
    return 0.5f * x * (1.0f + t);
}

// ---- async global->LDS 16B/lane. LDS dest = wave-uniform base + lane*16 (m104/m108). ----
__device__ __forceinline__ void glds16(const bf16* g, const bf16* l) {
    __builtin_amdgcn_global_load_lds(
        (const __attribute__((address_space(1))) void*)(uintptr_t)(const void*)g,
        (__attribute__((address_space(3))) void*)(unsigned)(uintptr_t)(const void*)l,
        16, 0, 0);
}

// ---------------- fp32 -> bf16 convert, 8 elems/thread ----------------
__global__ __launch_bounds__(256) void conv_kernel(
    const float* __restrict__ src, bf16* __restrict__ dst, int n8)
{
    int i = blockIdx.x * 256 + threadIdx.x;
    if (i >= n8) return;
    f32x4 a = *(const f32x4*)(src + (size_t)i * 8);
    f32x4 b = *(const f32x4*)(src + (size_t)i * 8 + 4);
    bf16x8 v;
#pragma unroll
    for (int j = 0; j < 4; j++) { v[j] = (bf16)a[j]; v[4 + j] = (bf16)b[j]; }
    *(bf16x8*)(dst + (size_t)i * 8) = v;
}

// ---------------- fused LayerNorm: fp32 row -> bf16 row, one block/row ----------------
__global__ __launch_bounds__(256) void ln_kernel(
    const float* __restrict__ x, const float* __restrict__ g, const float* __restrict__ b,
    bf16* __restrict__ out)
{
    const int row = blockIdx.x, t = threadIdx.x;
    f32x4 v = *(const f32x4*)(x + (size_t)row * DD + t * 4);
    float s  = v[0] + v[1] + v[2] + v[3];
    float s2 = v[0]*v[0] + v[1]*v[1] + v[2]*v[2] + v[3]*v[3];
#pragma unroll
    for (int off = 32; off >= 1; off >>= 1) {
        s  += __shfl_xor(s,  off, 64);
        s2 += __shfl_xor(s2, off, 64);
    }
    __shared__ float red[8];
    const int wave = t >> 6;
    if ((t & 63) == 0) { red[wave] = s; red[4 + wave] = s2; }
    __syncthreads();
    float ts  = red[0] + red[1] + red[2] + red[3];
    float ts2 = red[4] + red[5] + red[6] + red[7];
    float mean = ts * (1.0f / DD);
    float var  = ts2 * (1.0f / DD) - mean * mean;
    float rstd = rsqrtf(var + 1e-5f);
    f32x4 gv = *(const f32x4*)(g + t * 4);
    f32x4 bv = *(const f32x4*)(b + t * 4);
    bf16x4 o;
#pragma unroll
    for (int i = 0; i < 4; i++) o[i] = (bf16)((v[i] - mean) * rstd * gv[i] + bv[i]);
    *(bf16x4*)(out + (size_t)row * DD + t * 4) = o;
}

// ------- bf16 MFMA GEMM, glds staging: C[M,N] = A[M,K] @ W[N,K]^T + bias -------
// TM=128: waves 2x2, 4x4 frags. TM=64: waves 1x4, 4x2 frags. BN=128, 256 thr.
// BK: 32 (R7-proven control path) or 64 (experimental: half the barriers).
// Staging: each glds16 chunk = 256 threads x 16B = 2048 bf16 = (2048/BK) rows.
// ACT: 1=gelu. RESID: 2=add fp32 resid (may alias fp32 Cout: same elem, same
// thread, read-before-write). OUTF32: 1=fp32 out, 0=bf16.
template<int TM, int BK, int ACT, int RESID, int OUTF32>
__global__ __launch_bounds__(256) void gemm_glds(
    const bf16* __restrict__ A, const bf16* __restrict__ Bw,
    const float* __restrict__ bias,
    const float* resid, void* __restrict__ Cout, int N, int K)
{
    constexpr int MI = 4;
    constexpr int NJ = (TM == 128) ? 4 : 2;
    constexpr int CHROWS = 2048 / BK;          // rows per glds chunk (BK=32 -> 64, BK=64 -> 32)
    constexpr int CH_A = TM / CHROWS;
    constexpr int CH_B = 128 / CHROWS;
    __shared__ __align__(16) bf16 As[TM * BK];
    __shared__ __align__(16) bf16 Bs[128 * BK];
    const int t = threadIdx.x;
    const int m0 = blockIdx.y * TM, n0 = blockIdx.x * 128;
    const int lane = t & 63, w = t >> 6;
    const int wm = (TM == 128) ? (w & 1) * 64 : 0;
    const int wn = (TM == 128) ? (w >> 1) * 64 : w * 32;
    const int quad = lane >> 4, l16 = lane & 15;
    const int srow = t / (BK / 8);             // BK=32: t>>2 ; BK=64: t>>3
    const int scol = (t % (BK / 8)) * 8;

    const bf16* Ag = A  + (size_t)(m0 + srow) * K + scol;
    const bf16* Bg = Bw + (size_t)(n0 + srow) * K + scol;
    const bf16* AsW = As + w * 512;   // wave-uniform base; each chunk spans 2048 elems
    const bf16* BsW = Bs + w * 512;

    const f32x4 zero = {0.f, 0.f, 0.f, 0.f};
    f32x4 acc[MI][NJ];
#pragma unroll
    for (int i = 0; i < MI; i++)
#pragma unroll
        for (int j = 0; j < NJ; j++) acc[i][j] = zero;

    for (int k0 = 0; k0 < K; k0 += BK) {
        __syncthreads();                       // all waves done reading previous tile
#pragma unroll
        for (int r = 0; r < CH_A; r++)
            glds16(Ag + (size_t)(r * CHROWS) * K + k0, AsW + r * 2048);
#pragma unroll
        for (int r = 0; r < CH_B; r++)
            glds16(Bg + (size_t)(r * CHROWS) * K + k0, BsW + r * 2048);
        __syncthreads();                       // drains vmcnt -> LDS tiles visible
#pragma unroll
        for (int c = 0; c < BK / 32; c++) {
            bf16x8 af[MI], bfr[NJ];
#pragma unroll
            for (int i = 0; i < MI; i++)
                af[i] = *(const bf16x8*)(As + (wm + i * 16 + l16) * BK + c * 32 + quad * 8);
#pragma unroll
            for (int j = 0; j < NJ; j++)
                bfr[j] = *(const bf16x8*)(Bs + (wn + j * 16 + l16) * BK + c * 32 + quad * 8);
#pragma unroll
            for (int i = 0; i < MI; i++)
#pragma unroll
                for (int j = 0; j < NJ; j++)
                    acc[i][j] = __builtin_amdgcn_mfma_f32_16x16x32_bf16(af[i], bfr[j], acc[i][j], 0, 0, 0);
        }
    }

#pragma unroll
    for (int i = 0; i < MI; i++) {
#pragma unroll
        for (int j = 0; j < NJ; j++) {
            int col = n0 + wn + j * 16 + l16;
            float bv = bias[col];
#pragma unroll
            for (int r = 0; r < 4; r++) {
                int row = m0 + wm + i * 16 + quad * 4 + r;
                float val = acc[i][j][r] + bv;
                if (ACT == 1) val = gelu_f(val);
                size_t idx = (size_t)row * N + col;
                if (RESID == 2) val += resid[idx];
                if (OUTF32) ((float*)Cout)[idx] = val;
                else        ((bf16*)Cout)[idx] = (bf16)val;
            }
        }
    }
}

// ---------------- Sliding-window causal attention: one wave per (b,h,q) ----------------
__global__ __launch_bounds__(256) void attn_kernel(
    const bf16* __restrict__ qkv, bf16* __restrict__ o)
{
    const int gw = blockIdx.x * 4 + (threadIdx.x >> 6);
    const int lane = threadIdx.x & 63;
    const int q = gw & (SS - 1);
    const int h = (gw >> 11) & (HH - 1);
    const int b = gw >> 15;
    const size_t rowstride = 3 * DD;
    const bf16* base = qkv + (size_t)b * SS * rowstride + h * HDD + lane;
    float qd = (float)base[(size_t)q * rowstride] * 0.125f;  // 1/sqrt(64)
    float kv[WW], vv[WW];
#pragma unroll
    for (int j = 0; j < WW; j++) {
        int key = q - (WW - 1) + j;
        int kc = key < 0 ? 0 : key;
        const bf16* kp = base + (size_t)kc * rowstride + DD;
        kv[j] = (float)kp[0];
        vv[j] = (float)kp[DD];
    }
    float sc[WW];
#pragma unroll
    for (int j = 0; j < WW; j++) {
        float p = qd * kv[j];
        p += __shfl_xor(p, 32, 64);
        p += __shfl_xor(p, 16, 64);
        p += __shfl_xor(p,  8, 64);
        p += __shfl_xor(p,  4, 64);
        p += __shfl_xor(p,  2, 64);
        p += __shfl_xor(p,  1, 64);
        sc[j] = (q - (WW - 1) + j >= 0) ? p : -1e30f;
    }
    float m = sc[0];
#pragma unroll
    for (int j = 1; j < WW; j++) m = fmaxf(m, sc[j]);
    float l = 0.f, od = 0.f;
#pragma unroll
    for (int j = 0; j < WW; j++) {
        float e = __expf(sc[j] - m);
        l += e;
        od += e * vv[j];
    }
    o[(size_t)(b * SS + q) * DD + h * HDD + lane] = (bf16)(od / l);
}

// ---------------- launch ----------------
extern "C" void kernel_launch(void* const* d_in, const int* in_sizes, int n_in,
                              void* d_out, int out_size, void* d_ws, size_t ws_size,
                              hipStream_t stream)
{
    (void)in_sizes; (void)n_in; (void)out_size; (void)ws_size;
    const float* x    = (const float*)d_in[0];
    const float* ln1g = (const float*)d_in[1];
    const float* ln1b = (const float*)d_in[2];
    const float* Wqkv = (const float*)d_in[3];
    const float* bqkv = (const float*)d_in[4];
    const float* Wout = (const float*)d_in[5];
    const float* bout = (const float*)d_in[6];
    const float* ln2g = (const float*)d_in[7];
    const float* ln2b = (const float*)d_in[8];
    const float* W1   = (const float*)d_in[9];
    const float* b1   = (const float*)d_in[10];
    const float* W2   = (const float*)d_in[11];
    const float* b2   = (const float*)d_in[12];

    // Workspace (56 MiB peak; layout proven safe in R7/R8):
    //   [0,16M)  W region. Phase A: Wqkv_bf @0..6M, Wout_bf @6..8M.
    //            Phase B: W1_bf @0..8M, W2_bf @8..16M.
    //   [16,48M) P region. Phase A: qkv bf16 24 MiB. Phase B: h1 bf16 32 MiB.
    //   [48,56M) H region: h (LN1 out) -> o (attn out) -> xn (LN2 out), serially.
    //   x1 fp32 lives in d_out; MLP2 adds residual in-place (same elem, same thread).
    const size_t MB = (size_t)1 << 20;
    char* ws = (char*)d_ws;
    bf16* wqkv_bf = (bf16*)(ws);
    bf16* wout_bf = (bf16*)(ws + 6 * MB);
    bf16* w1_bf   = (bf16*)(ws);
    bf16* w2_bf   = (bf16*)(ws + 8 * MB);
    bf16* qkv     = (bf16*)(ws + 16 * MB);
    bf16* h1      = (bf16*)(ws + 16 * MB);
    bf16* hbuf    = (bf16*)(ws + 48 * MB);   // h, then o, then xn
    float* x1     = (float*)d_out;

    const dim3 blk(256);

    // Phase A: weights for QKV + out-proj
    conv_kernel<<<(3 * DD * DD / 8) / 256, blk, 0, stream>>>(Wqkv, wqkv_bf, 3 * DD * DD / 8);
    conv_kernel<<<(DD * DD / 8) / 256, blk, 0, stream>>>(Wout, wout_bf, DD * DD / 8);
    // h = LN1(x)
    ln_kernel<<<NTOK, blk, 0, stream>>>(x, ln1g, ln1b, hbuf);
    // qkv = h @ Wqkv^T + bqkv           (M=4096, N=3072, K=1024)  [BK=64 experiment]
    gemm_glds<128, 64, 0, 0, 0><<<dim3(24, 32), blk, 0, stream>>>(
        hbuf, wqkv_bf, bqkv, nullptr, qkv, 3 * DD, DD);
    // o = attention(qkv)  (o overwrites h — h dead)
    attn_kernel<<<BB * HH * SS / 4, blk, 0, stream>>>(qkv, hbuf);
    // x1 = x + o @ Wout^T + bout        (fp32 into d_out; M=4096, N=1024, K=1024)  [R7 control]
    gemm_glds<64, 32, 0, 2, 1><<<dim3(8, 64), blk, 0, stream>>>(
        hbuf, wout_bf, bout, x, x1, DD, DD);

    // Phase B: weights for MLP
    conv_kernel<<<(DFFD * DD / 8) / 256, blk, 0, stream>>>(W1, w1_bf, DFFD * DD / 8);
    conv_kernel<<<(DFFD * DD / 8) / 256, blk, 0, stream>>>(W2, w2_bf, DFFD * DD / 8);
    // xn = LN2(x1)   (xn overwrites o — o dead)
    ln_kernel<<<NTOK, blk, 0, stream>>>(x1, ln2g, ln2b, hbuf);
    // h1 = gelu(xn @ W1^T + b1)         (M=4096, N=4096, K=1024)  [BK=64 experiment]
    gemm_glds<128, 64, 1, 0, 0><<<dim3(32, 32), blk, 0, stream>>>(
        hbuf, w1_bf, b1, nullptr, h1, DFFD, DD);
    // out = x1 + h1 @ W2^T + b2         (fp32 in-place; M=4096, N=1024, K=4096)  [R7 control]
    gemm_glds<64, 32, 0, 2, 1><<<dim3(8, 64), blk, 0, stream>>>(
        h1, w2_bf, b2, x1, x1, DD, DFFD);
}